// Round 4
// baseline (588.414 us; speedup 1.0000x reference)
//
#include <hip/hip_runtime.h>
#include <hip/hip_bf16.h>
#include <math.h>

// Problem constants (from reference): B=128, N=2048, M=128
#define BB 128
#define NN 2048
#define MM 128
#define ROWS 128                      // n-rows per block
#define CHUNKS (NN / ROWS)            // 16 blocks per batch row
#define STRIDE (MM + 4)               // 132 words: every row 16B-aligned
#define OFFSET_EPS 1e-6f
#define COS_EPS 1e-8f

// ---------------------------------------------------------------------------
// Fused kernel. Grid = B*CHUNKS = 2048 blocks x 256 threads.
// Each block:
//   phase 1: coalesced float4 stage of its 128-row tile (global->LDS),
//            colsum partials in registers (thread's column group fixed).
//   phase 2: thread t serially reduces half-row (r=t>>1,h=t&1) from LDS,
//            one __shfl_xor(1) combine; writes score[b,n]=beta*cos.
//            eps folded: dot = Sum v*k' + eps*Sum k';
//                        nm^2 = Sum v^2 + 2 eps Sum v + M eps^2.
//   fan-in:  __threadfence(); atomicAdd(done[b]). Last of the 16 blocks for
//            this b runs the epilogue (softmax WITHOUT max-subtraction —
//            scores in [-1,1] — plus S = sum(w_prev^gamma)+eps and the
//            closed-form r_t), overlapping other b's streaming work.
// LDS ~72 KB -> 2 blocks/CU; HBM-bound streaming (134 MB read).
// ---------------------------------------------------------------------------
__global__ __launch_bounds__(256) void fused(
    const float* __restrict__ memory, const float* __restrict__ k_t,
    const float* __restrict__ beta_t, const float* __restrict__ g_t,
    const float* __restrict__ w_prev, const float* __restrict__ gamma_t,
    const float* __restrict__ e_t,    const float* __restrict__ a_t,
    float* __restrict__ colsum_part,  float* __restrict__ score,
    unsigned int* __restrict__ done,  float* __restrict__ out)
{
    __shared__ float tile[ROWS * STRIDE];
    __shared__ float ks[MM];          // k + eps
    __shared__ float s_col[8][MM];    // colsum partials per thread-group
    __shared__ float s_bon;           // beta / nk
    __shared__ float s_epsK1;         // eps * Sum(k+eps)
    __shared__ unsigned int s_flag;
    __shared__ float s_red[8];

    const int b     = blockIdx.x / CHUNKS;
    const int chunk = blockIdx.x % CHUNKS;
    const int r0    = chunk * ROWS;
    const int t     = threadIdx.x;

    // ---- k' staging + per-b constants (wave-0 lanes 0..31) ----
    if (t < 32) {
        float4 kv = *(const float4*)(k_t + b * MM + 4 * t);
        const float e0 = kv.x + OFFSET_EPS, e1 = kv.y + OFFSET_EPS,
                    e2 = kv.z + OFFSET_EPS, e3 = kv.w + OFFSET_EPS;
        *(float4*)&ks[4 * t] = make_float4(e0, e1, e2, e3);
        float s2 = e0 * e0 + e1 * e1 + e2 * e2 + e3 * e3;
        float s1 = e0 + e1 + e2 + e3;
        #pragma unroll
        for (int s = 16; s; s >>= 1) {
            s2 += __shfl_xor(s2, s);
            s1 += __shfl_xor(s1, s);
        }
        if (t == 0) {
            s_bon   = beta_t[b] / fmaxf(sqrtf(s2), COS_EPS);
            s_epsK1 = OFFSET_EPS * s1;
        }
    }

    // ---- phase 1: coalesced staging + colsum register partials ----
    const float* src = memory + (size_t)(b * NN + r0) * MM;
    float cs0 = 0.f, cs1 = 0.f, cs2 = 0.f, cs3 = 0.f;
    #pragma unroll
    for (int i = 0; i < 16; ++i) {
        float4 v = *(const float4*)(src + i * 1024 + 4 * t);
        cs0 += v.x; cs1 += v.y; cs2 += v.z; cs3 += v.w;   // raw memory
        const int row = i * 8 + (t >> 5);
        const int col = (4 * t) & 127;
        *(float4*)&tile[row * STRIDE + col] = v;
    }
    *(float4*)&s_col[t >> 5][(4 * t) & 127] = make_float4(cs0, cs1, cs2, cs3);
    __syncthreads();

    // ---- phase 2: serial half-row reduce from LDS ----
    const int r = t >> 1;
    const int h = t & 1;
    const float* vrow = &tile[r * STRIDE + h * 64];
    const float* krow = &ks[h * 64];
    float dot = 0.f, sq = 0.f, rs = 0.f;
    #pragma unroll
    for (int j = 0; j < 16; ++j) {
        float4 v = *(const float4*)(vrow + 4 * j);
        float4 k = *(const float4*)(krow + 4 * j);
        dot += v.x * k.x + v.y * k.y + v.z * k.z + v.w * k.w;
        sq  += v.x * v.x + v.y * v.y + v.z * v.z + v.w * v.w;
        rs  += v.x + v.y + v.z + v.w;
    }
    dot += __shfl_xor(dot, 1);
    sq  += __shfl_xor(sq, 1);
    rs  += __shfl_xor(rs, 1);
    if (h == 0) {
        const float d   = dot + s_epsK1;
        const float nm2 = sq + 2.0f * OFFSET_EPS * rs
                          + (float)MM * OFFSET_EPS * OFFSET_EPS;
        const float nm  = fmaxf(sqrtf(nm2), COS_EPS);
        score[b * NN + r0 + r] = d * s_bon / nm;
    }

    // ---- colsum partial write (threads 0..127) ----
    if (t < MM) {
        float v = 0.f;
        #pragma unroll
        for (int g = 0; g < 8; ++g) v += s_col[g][t];
        colsum_part[(size_t)chunk * (BB * MM) + b * MM + t] = v;
    }

    // ---- fan-in: last of the 16 blocks for this b runs the epilogue ----
    __threadfence();               // make this thread's writes device-visible
    __syncthreads();               // all threads' fences complete
    if (t == 0) s_flag = atomicAdd(&done[b], 1u);
    __syncthreads();
    if (s_flag != CHUNKS - 1) return;
    __threadfence();               // acquire: order/invalidate before reads

    // ===================== epilogue (one block per b) =====================
    const float g     = g_t[b];
    const float gamma = gamma_t[b];
    float ex[8], wv[8];
    float esum = 0.f, psum = 0.f;
    #pragma unroll
    for (int i = 0; i < 8; ++i) {
        const int n = t + 256 * i;
        ex[i] = __expf(score[b * NN + n]);     // scores in [-1,1]: no max sub
        esum += ex[i];
        wv[i] = w_prev[b * NN + n];
        psum += __powf(wv[i], gamma);          // w in [0,1): safe
    }
    #pragma unroll
    for (int s = 32; s; s >>= 1) {             // 64-lane butterflies
        esum += __shfl_xor(esum, s);
        psum += __shfl_xor(psum, s);
    }
    const int wave = t >> 6;
    const int lane = t & 63;
    if (lane == 0) { s_red[wave] = esum; s_red[4 + wave] = psum; }
    __syncthreads();
    const float inv_sum = 1.f / (s_red[0] + s_red[1] + s_red[2] + s_red[3]);
    const float S = (s_red[4] + s_red[5] + s_red[6] + s_red[7]) + OFFSET_EPS;

    float* orow = out + (size_t)b * (MM + 2 * NN);
    #pragma unroll
    for (int i = 0; i < 8; ++i) {
        const int n = t + 256 * i;
        orow[MM + n]      = S;                              // w_t broadcast
        orow[MM + NN + n] = g * ex[i] * inv_sum + (1.f - g) * wv[i];  // w_g
    }
    if (t < MM) {
        float cs = 0.f;
        #pragma unroll
        for (int c = 0; c < CHUNKS; ++c)
            cs += colsum_part[(size_t)c * (BB * MM) + b * MM + t];
        const float rr = S * ((1.f - S * e_t[b * MM + t]) * cs +
                              (float)NN * S * a_t[b * MM + t]);
        orow[t] = rr;
    }
}

extern "C" void kernel_launch(void* const* d_in, const int* in_sizes, int n_in,
                              void* d_out, int out_size, void* d_ws, size_t ws_size,
                              hipStream_t stream) {
    const float* memory  = (const float*)d_in[0];
    const float* k_t     = (const float*)d_in[1];
    const float* beta_t  = (const float*)d_in[2];
    const float* g_t     = (const float*)d_in[3];
    const float* w_prev  = (const float*)d_in[4];
    // d_in[5] = s_t (unused by the live output chains)
    const float* gamma_t = (const float*)d_in[6];
    const float* e_t     = (const float*)d_in[7];
    const float* a_t     = (const float*)d_in[8];
    float* out = (float*)d_out;

    // workspace layout: [colsum_part CHUNKS*B*M | score B*N | done B]
    float* colsum_part = (float*)d_ws;
    float* score       = colsum_part + CHUNKS * BB * MM;
    unsigned int* done = (unsigned int*)(score + BB * NN);

    hipMemsetAsync(done, 0, BB * sizeof(unsigned int), stream);

    fused<<<BB * CHUNKS, 256, 0, stream>>>(memory, k_t, beta_t, g_t, w_prev,
                                           gamma_t, e_t, a_t,
                                           colsum_part, score, done, out);
}

// Round 5
// 208.602 us; speedup vs baseline: 2.8208x; 2.8208x over previous
//
#include <hip/hip_runtime.h>
#include <hip/hip_bf16.h>
#include <math.h>

// Problem constants (from reference): B=128, N=2048, M=128
#define BB 128
#define NN 2048
#define MM 128
#define ROWS 64                       // n-rows per pass_a block
#define CHUNKS (NN / ROWS)            // 32 blocks per batch row
#define STRIDE (MM + 4)               // 132 words: rows 16B-aligned
#define OFFSET_EPS 1e-6f
#define COS_EPS 1e-8f

// ---------------------------------------------------------------------------
// Pass A: one coalesced read of memory[B,N,M]. Per 64-row chunk it emits:
//   ex_buf[b,n]            = exp(beta*cos(memory[b,n,:]+eps, k+eps))  (no max
//                            subtraction: scores in [-1,1], exp in [.37,2.7])
//   colsum_part[c,b,m]     = chunk column sums of raw memory
//   esum_part[c,b]         = chunk sum of ex
//   psum_part[c,b]         = chunk sum of w_prev^gamma
// Structure: float4 stage to LDS tile (colsum in registers during staging),
// then quarter-row serial reduce from LDS + 2-step shfl combine. eps folded:
// dot = Sum v*k' + eps*Sum k'; nm^2 = Sum v^2 + 2 eps Sum v + M eps^2.
// LDS ~38.5 KB -> 4 blocks/CU (R3 was 72KB/2 blocks; more latency hiding).
// NO device-scope fences (R4 fan-in fence cost ~470us — never again).
// ---------------------------------------------------------------------------
__global__ __launch_bounds__(256) void pass_a(
    const float* __restrict__ memory, const float* __restrict__ k_t,
    const float* __restrict__ beta_t, const float* __restrict__ w_prev,
    const float* __restrict__ gamma_t,
    float* __restrict__ colsum_part, float* __restrict__ ex_buf,
    float* __restrict__ esum_part,   float* __restrict__ psum_part)
{
    __shared__ float tile[ROWS * STRIDE];   // 33792 B
    __shared__ float ks[MM];                // k + eps
    __shared__ float s_col[8][MM];          // colsum partials per row-group
    __shared__ float s_red[4];              // per-wave esum
    __shared__ float s_bon;                 // beta / nk
    __shared__ float s_epsK1;               // eps * Sum(k+eps)

    const int b     = blockIdx.x / CHUNKS;
    const int chunk = blockIdx.x % CHUNKS;
    const int r0    = chunk * ROWS;
    const int t     = threadIdx.x;

    // ---- k' staging + per-b constants (wave-0 lanes 0..31) ----
    if (t < 32) {
        float4 kv = *(const float4*)(k_t + b * MM + 4 * t);
        const float e0 = kv.x + OFFSET_EPS, e1 = kv.y + OFFSET_EPS,
                    e2 = kv.z + OFFSET_EPS, e3 = kv.w + OFFSET_EPS;
        *(float4*)&ks[4 * t] = make_float4(e0, e1, e2, e3);
        float s2 = e0 * e0 + e1 * e1 + e2 * e2 + e3 * e3;
        float s1 = e0 + e1 + e2 + e3;
        #pragma unroll
        for (int s = 16; s; s >>= 1) {
            s2 += __shfl_xor(s2, s);
            s1 += __shfl_xor(s1, s);
        }
        if (t == 0) {
            s_bon   = beta_t[b] / fmaxf(sqrtf(s2), COS_EPS);
            s_epsK1 = OFFSET_EPS * s1;
        }
    }

    // ---- psum partial: w_prev^gamma over this chunk's 64 rows (t<16) ----
    if (t < 16) {
        float4 w = *(const float4*)(w_prev + b * NN + r0 + 4 * t);
        const float gamma = gamma_t[b];
        float p = __powf(w.x, gamma) + __powf(w.y, gamma) +
                  __powf(w.z, gamma) + __powf(w.w, gamma);   // w in [0,1)
        #pragma unroll
        for (int s = 8; s; s >>= 1) p += __shfl_xor(p, s);
        if (t == 0) psum_part[chunk * BB + b] = p;
    }

    // ---- phase 1: coalesced staging + colsum register partials ----
    const float* src = memory + (size_t)(b * NN + r0) * MM;
    float cs0 = 0.f, cs1 = 0.f, cs2 = 0.f, cs3 = 0.f;
    #pragma unroll
    for (int i = 0; i < 8; ++i) {
        float4 v = *(const float4*)(src + i * 1024 + 4 * t);
        cs0 += v.x; cs1 += v.y; cs2 += v.z; cs3 += v.w;   // raw memory
        const int row = i * 8 + (t >> 5);
        const int col = (4 * t) & 127;
        *(float4*)&tile[row * STRIDE + col] = v;
    }
    *(float4*)&s_col[t >> 5][(4 * t) & 127] = make_float4(cs0, cs1, cs2, cs3);
    __syncthreads();

    // ---- phase 2: quarter-row serial reduce from LDS ----
    const int r = t >> 2;     // 0..63
    const int q = t & 3;      // 32-float segment
    const float* vrow = &tile[r * STRIDE + q * 32];
    const float* krow = &ks[q * 32];
    float dot = 0.f, sq = 0.f, rs = 0.f;
    #pragma unroll
    for (int j = 0; j < 8; ++j) {
        float4 v = *(const float4*)(vrow + 4 * j);
        float4 k = *(const float4*)(krow + 4 * j);
        dot += v.x * k.x + v.y * k.y + v.z * k.z + v.w * k.w;
        sq  += v.x * v.x + v.y * v.y + v.z * v.z + v.w * v.w;
        rs  += v.x + v.y + v.z + v.w;
    }
    dot += __shfl_xor(dot, 1); dot += __shfl_xor(dot, 2);
    sq  += __shfl_xor(sq, 1);  sq  += __shfl_xor(sq, 2);
    rs  += __shfl_xor(rs, 1);  rs  += __shfl_xor(rs, 2);

    float ex = 0.f;
    if (q == 0) {
        const float d   = dot + s_epsK1;
        const float nm2 = sq + 2.0f * OFFSET_EPS * rs
                          + (float)MM * OFFSET_EPS * OFFSET_EPS;
        const float sc  = d * s_bon / fmaxf(sqrtf(nm2), COS_EPS);
        ex = __expf(sc);
        ex_buf[b * NN + r0 + r] = ex;
    }
    // esum: full-wave butterfly (q!=0 lanes contribute 0)
    float es = ex;
    #pragma unroll
    for (int s = 32; s; s >>= 1) es += __shfl_xor(es, s);
    if ((t & 63) == 0) s_red[t >> 6] = es;
    __syncthreads();
    if (t == 0)
        esum_part[chunk * BB + b] = s_red[0] + s_red[1] + s_red[2] + s_red[3];

    // ---- colsum combine (threads 0..127, one column each) ----
    if (t < MM) {
        float v = 0.f;
        #pragma unroll
        for (int g = 0; g < 8; ++g) v += s_col[g][t];
        colsum_part[(size_t)chunk * (BB * MM) + b * MM + t] = v;
    }
}

// ---------------------------------------------------------------------------
// Pass B: pure streaming epilogue. Grid = 2 blocks per b (256 blocks total),
// each block covers 1024 n's with one float4 sweep. Only reduction is a
// 32-element scalar partial combine on thread 0.
// out[b, 0:M)      = r_t = S*((1-S*e)*colsum + N*S*a)
// out[b, M:M+N)    = w_t = S (broadcast)
// out[b, M+N:M+2N) = w_g = g*ex/esum + (1-g)*w_prev
// ---------------------------------------------------------------------------
__global__ __launch_bounds__(256) void pass_b(
    const float* __restrict__ ex_buf, const float* __restrict__ g_t,
    const float* __restrict__ w_prev, const float* __restrict__ e_t,
    const float* __restrict__ a_t,    const float* __restrict__ colsum_part,
    const float* __restrict__ esum_part, const float* __restrict__ psum_part,
    float* __restrict__ out)
{
    const int b    = blockIdx.x >> 1;
    const int half = blockIdx.x & 1;
    const int t    = threadIdx.x;
    __shared__ float s_inv, s_S;

    if (t == 0) {
        float es = 0.f, ps = 0.f;
        #pragma unroll
        for (int c = 0; c < CHUNKS; ++c) {
            es += esum_part[c * BB + b];
            ps += psum_part[c * BB + b];
        }
        s_inv = 1.f / es;
        s_S   = ps + OFFSET_EPS;
    }
    __syncthreads();
    const float inv = s_inv, S = s_S, g = g_t[b];

    float* orow = out + (size_t)b * (MM + 2 * NN);
    const int n0 = half * 1024 + 4 * t;
    float4 ex4 = *(const float4*)(ex_buf + b * NN + n0);
    float4 w4  = *(const float4*)(w_prev + b * NN + n0);
    float4 wg;
    wg.x = g * ex4.x * inv + (1.f - g) * w4.x;
    wg.y = g * ex4.y * inv + (1.f - g) * w4.y;
    wg.z = g * ex4.z * inv + (1.f - g) * w4.z;
    wg.w = g * ex4.w * inv + (1.f - g) * w4.w;
    *(float4*)(orow + MM + n0)      = make_float4(S, S, S, S);  // w_t
    *(float4*)(orow + MM + NN + n0) = wg;                       // w_g

    if (half == 0 && t < MM) {
        float cs = 0.f;
        #pragma unroll
        for (int c = 0; c < CHUNKS; ++c)
            cs += colsum_part[(size_t)c * (BB * MM) + b * MM + t];
        orow[t] = S * ((1.f - S * e_t[b * MM + t]) * cs +
                       (float)NN * S * a_t[b * MM + t]);
    }
}

extern "C" void kernel_launch(void* const* d_in, const int* in_sizes, int n_in,
                              void* d_out, int out_size, void* d_ws, size_t ws_size,
                              hipStream_t stream) {
    const float* memory  = (const float*)d_in[0];
    const float* k_t     = (const float*)d_in[1];
    const float* beta_t  = (const float*)d_in[2];
    const float* g_t     = (const float*)d_in[3];
    const float* w_prev  = (const float*)d_in[4];
    // d_in[5] = s_t (unused by the live output chains)
    const float* gamma_t = (const float*)d_in[6];
    const float* e_t     = (const float*)d_in[7];
    const float* a_t     = (const float*)d_in[8];
    float* out = (float*)d_out;

    // ws layout: [colsum_part CHUNKS*B*M | ex B*N | esum CHUNKS*B | psum ...]
    float* colsum_part = (float*)d_ws;
    float* ex_buf      = colsum_part + (size_t)CHUNKS * BB * MM;
    float* esum_part   = ex_buf + BB * NN;
    float* psum_part   = esum_part + CHUNKS * BB;

    pass_a<<<BB * CHUNKS, 256, 0, stream>>>(memory, k_t, beta_t, w_prev,
                                            gamma_t, colsum_part, ex_buf,
                                            esum_part, psum_part);
    pass_b<<<2 * BB, 256, 0, stream>>>(ex_buf, g_t, w_prev, e_t, a_t,
                                       colsum_part, esum_part, psum_part, out);
}